// Round 6
// baseline (122.696 us; speedup 1.0000x reference)
//
#include <hip/hip_runtime.h>
#include <hip/hip_bf16.h>
#include <stdint.h>

#define ALPHA 0.2f

typedef __attribute__((ext_vector_type(8))) short short8;
typedef __attribute__((ext_vector_type(4))) float f32x4;

__device__ inline short f2bf(float x) {
    union { __hip_bfloat16 b; short s; } u;
    u.b = __float2bfloat16(x);
    return u.s;
}

__device__ inline void gload16(const short* g, short* l) {
    __builtin_amdgcn_global_load_lds((const __attribute__((address_space(1))) unsigned int*)g,
                                     (__attribute__((address_space(3))) unsigned int*)l, 16, 0, 0);
}

// ---------------- Kernel A: Wh = h@W fp32 (4x4 reg-blocked) + WhT bf16 + f1/f2 + mask-pack ---
__global__ __launch_bounds__(256) void kA(const float* __restrict__ h,
                                          const float* __restrict__ W,
                                          const float* __restrict__ av,
                                          const float* __restrict__ adj,
                                          short* __restrict__ whT,
                                          float* __restrict__ f1g,
                                          float* __restrict__ f2g,
                                          uint32_t* __restrict__ maskg) {
    int blk = blockIdx.x;
    int b  = blk >> 6;
    int n0 = (blk & 63) * 32;
    __shared__ float hl[32 * 128];
    __shared__ float wh[32 * 132];
    __shared__ float plds[32 * 8 * 2];
    int t = threadIdx.x;

    {
        int gt = blk * 256 + t;
        int mi = gt >> 6, wd = gt & 63;
        const float* src = adj + (size_t)mi * 2048 + wd * 32;
        uint32_t m = 0;
        #pragma unroll
        for (int k = 0; k < 32; k += 4) {
            f32x4 v = *reinterpret_cast<const f32x4*>(src + k);
            if (v[0] > 0.f) m |= 1u << (k + 0);
            if (v[1] > 0.f) m |= 1u << (k + 1);
            if (v[2] > 0.f) m |= 1u << (k + 2);
            if (v[3] > 0.f) m |= 1u << (k + 3);
        }
        maskg[mi * 64 + wd] = m;
    }

    const f32x4* hs = reinterpret_cast<const f32x4*>(h + ((size_t)(b * 2048 + n0)) * 128);
    f32x4* h4 = reinterpret_cast<f32x4*>(hl);
    #pragma unroll
    for (int k = 0; k < 4; k++) h4[t + k * 256] = hs[t + k * 256];
    __syncthreads();

    int og = t & 31, rg = t >> 5;
    int o0 = og * 4, r0 = rg * 4;
    f32x4 acc0 = {0.f,0.f,0.f,0.f}, acc1 = {0.f,0.f,0.f,0.f};
    f32x4 acc2 = {0.f,0.f,0.f,0.f}, acc3 = {0.f,0.f,0.f,0.f};
    const f32x4* W4  = reinterpret_cast<const f32x4*>(W);
    const f32x4* hv4 = reinterpret_cast<const f32x4*>(hl);
    #pragma unroll 4
    for (int f0 = 0; f0 < 128; f0 += 4) {
        f32x4 h0 = hv4[(r0 + 0) * 32 + (f0 >> 2)];
        f32x4 h1 = hv4[(r0 + 1) * 32 + (f0 >> 2)];
        f32x4 h2 = hv4[(r0 + 2) * 32 + (f0 >> 2)];
        f32x4 h3 = hv4[(r0 + 3) * 32 + (f0 >> 2)];
        f32x4 w0 = W4[(f0 + 0) * 32 + og];
        f32x4 w1 = W4[(f0 + 1) * 32 + og];
        f32x4 w2 = W4[(f0 + 2) * 32 + og];
        f32x4 w3 = W4[(f0 + 3) * 32 + og];
        acc0 += h0[0] * w0 + h0[1] * w1 + h0[2] * w2 + h0[3] * w3;
        acc1 += h1[0] * w0 + h1[1] * w1 + h1[2] * w2 + h1[3] * w3;
        acc2 += h2[0] * w0 + h2[1] * w1 + h2[2] * w2 + h2[3] * w3;
        acc3 += h3[0] * w0 + h3[1] * w1 + h3[2] * w2 + h3[3] * w3;
    }
    *reinterpret_cast<f32x4*>(&wh[(r0 + 0) * 132 + o0]) = acc0;
    *reinterpret_cast<f32x4*>(&wh[(r0 + 1) * 132 + o0]) = acc1;
    *reinterpret_cast<f32x4*>(&wh[(r0 + 2) * 132 + o0]) = acc2;
    *reinterpret_cast<f32x4*>(&wh[(r0 + 3) * 132 + o0]) = acc3;
    __syncthreads();

    {
        int o = t & 127, rg2 = t >> 7;
        short8 lo, hi;
        #pragma unroll
        for (int r = 0; r < 8; r++) lo[r] = f2bf(wh[(rg2 * 16 + r) * 132 + o]);
        #pragma unroll
        for (int r = 0; r < 8; r++) hi[r] = f2bf(wh[(rg2 * 16 + 8 + r) * 132 + o]);
        size_t base = ((size_t)(b * 128 + o)) * 2048 + n0 + rg2 * 16;
        *reinterpret_cast<short8*>(whT + base)     = lo;
        *reinterpret_cast<short8*>(whT + base + 8) = hi;
    }

    {
        int r = t & 31, og8 = t >> 5;
        float s1 = 0.f, s2 = 0.f;
        #pragma unroll
        for (int k = 0; k < 16; k++) {
            float v = wh[r * 132 + og8 * 16 + k];
            s1 += v * av[og8 * 16 + k];
            s2 += v * av[128 + og8 * 16 + k];
        }
        plds[(r * 8 + og8) * 2 + 0] = s1;
        plds[(r * 8 + og8) * 2 + 1] = s2;
    }
    __syncthreads();
    if (t < 64) {
        int r = t & 31, which = t >> 5;
        float s = 0.f;
        #pragma unroll
        for (int og8 = 0; og8 < 8; og8++) s += plds[(r * 8 + og8) * 2 + which];
        if (which == 0) f1g[b * 2048 + n0 + r] = s;
        else            f2g[b * 2048 + n0 + r] = s;
    }
}

// ---------------- Kernel G2: fused masked-softmax-GEMM, fully software-pipelined -----------
// grid 512: (b, 32i-tile). BK=32, 4-deep B-ring. Post-barrier chain = MFMA from ready regs;
// B-frags read one iter ahead, A-frags (exp) built two iters ahead from loop-invariant LDS.
__global__ __launch_bounds__(256) void kG2(const uint32_t* __restrict__ maskg,
                                           const short* __restrict__ whT,
                                           const float* __restrict__ f1g,
                                           const float* __restrict__ f2g,
                                           const float* __restrict__ bias,
                                           float* __restrict__ out) {
    int blk = blockIdx.x;
    int b      = blk >> 6;
    int i_tile = (blk & 63) * 32;
    int t = threadIdx.x;
    int w = t >> 6, lane = t & 63, il = lane & 15, quad = lane >> 4;
    int ihalf = w & 1, ohalf = w >> 1;
    int i_base = i_tile + ihalf * 16;
    int ow = ohalf * 64;

    __shared__ uint32_t m32l[32 * 68];
    __shared__ float    f2l[2048];
    __shared__ short    Bl[4][128 * 32];
    __shared__ float    lred[32 * 4];
    __shared__ float    linvl[32];

    // loop-invariant loads; force into regs before any staging gload so the
    // vmcnt queue afterwards contains ONLY ring loads.
    const uint4* msrc = reinterpret_cast<const uint4*>(maskg + (size_t)i_tile * 64);
    uint4 mv0 = msrc[t];
    uint4 mv1 = msrc[t + 256];
    const f32x4* fsrc = reinterpret_cast<const f32x4*>(f2g + b * 2048);
    f32x4 fv0 = fsrc[t];
    f32x4 fv1 = fsrc[t + 256];
    float f1v = f1g[b * 2048 + i_base + il];
    __asm__ __volatile__("" :: "v"(f1v));   // force f1v load completion ordering

    {
        int row0 = t >> 4, wq0 = (t & 15) * 4;
        *reinterpret_cast<uint4*>(&m32l[row0 * 68 + wq0]) = mv0;
        int idx = t + 256;
        int row1 = idx >> 4, wq1 = (idx & 15) * 4;
        *reinterpret_cast<uint4*>(&m32l[row1 * 68 + wq1]) = mv1;
        f32x4* fdst = reinterpret_cast<f32x4*>(f2l);
        fdst[t]       = fv0;
        fdst[t + 256] = fv1;
    }
    __asm__ __volatile__("" ::: "memory");

    // ring staging geometry
    int r = t >> 2, cs = t & 3;
    int rB1 = r + 64;
    const short* gB0 = whT + ((size_t)(b * 128 + r))   * 2048 + ((cs ^ ((r   >> 1) & 3)) << 3);
    const short* gB1 = whT + ((size_t)(b * 128 + rB1)) * 2048 + ((cs ^ ((rB1 >> 1) & 3)) << 3);
    int lslot = t * 8;

    #pragma unroll
    for (int p = 0; p < 3; p++) {
        gload16(gB0 + p * 32, &Bl[p][lslot]);
        gload16(gB1 + p * 32, &Bl[p][2048 + lslot]);
    }

    int sw = (quad ^ ((il >> 1) & 3)) << 3;
    int offB0 = (ow + 0  + il) * 32 + sw;
    int offB1 = (ow + 16 + il) * 32 + sw;
    int offB2 = (ow + 32 + il) * 32 + sw;
    int offB3 = (ow + 48 + il) * 32 + sw;
    int mrow = (ihalf * 16 + il) * 68;

    f32x4 acc0 = {0.f,0.f,0.f,0.f}, acc1 = {0.f,0.f,0.f,0.f};
    f32x4 acc2 = {0.f,0.f,0.f,0.f}, acc3 = {0.f,0.f,0.f,0.f};
    float lpart = 0.f;
    short8 afr[2];
    short8 bfr[2][4];

#define ABUILD(SLOT, KK) do {                                                    \
    uint32_t mw = m32l[mrow + (KK)];                                             \
    f32x4 q0 = *reinterpret_cast<const f32x4*>(&f2l[(KK) * 32 + quad * 8]);      \
    f32x4 q1 = *reinterpret_cast<const f32x4*>(&f2l[(KK) * 32 + quad * 8 + 4]);  \
    float es = 0.f;                                                              \
    _Pragma("unroll")                                                            \
    for (int k = 0; k < 8; k++) {                                                \
        float qv = (k < 4) ? q0[k] : q1[k - 4];                                  \
        float x = f1v + qv;                                                      \
        x = fmaxf(x, ALPHA * x);                                                 \
        float e = ((mw >> (quad * 8 + k)) & 1u) ? __expf(x) : 0.f;               \
        afr[SLOT][k] = f2bf(e); es += e;                                         \
    }                                                                            \
    if (ohalf == 0) lpart += es;                                                 \
} while (0)

#define BREAD(SLOT, KK) do {                                                     \
    const short* Bb = &Bl[(KK) & 3][0];                                          \
    bfr[SLOT][0] = *reinterpret_cast<const short8*>(Bb + offB0);                 \
    bfr[SLOT][1] = *reinterpret_cast<const short8*>(Bb + offB1);                 \
    bfr[SLOT][2] = *reinterpret_cast<const short8*>(Bb + offB2);                 \
    bfr[SLOT][3] = *reinterpret_cast<const short8*>(Bb + offB3);                 \
} while (0)

    // prologue: barrier for m32l/f2l, build af[0], af[1], pre-read B[0]
    __builtin_amdgcn_s_waitcnt(0xC07F);   // lgkmcnt(0)
    __builtin_amdgcn_s_barrier();
    __asm__ __volatile__("" ::: "memory");
    ABUILD(0, 0);
    ABUILD(1, 1);
    __builtin_amdgcn_s_waitcnt(0x0F74);   // vmcnt(4): tile 0 landed
    __asm__ __volatile__("" ::: "memory");
    BREAD(0, 0);

#define KSTEP(KB, WAITB, WAITN, STAGE, RDNEXT, NEXTA, CUR, NXT) do {             \
    if (WAITB) {                                                                 \
        __asm__ __volatile__("" ::: "memory");                                   \
        __builtin_amdgcn_s_waitcnt(0x0F70 | (WAITN));                            \
        __builtin_amdgcn_s_barrier();                                            \
        __asm__ __volatile__("" ::: "memory");                                   \
    }                                                                            \
    if (STAGE) {                                                                 \
        int ko = ((KB) + 3) * 32;                                                \
        gload16(gB0 + ko, &Bl[((KB) + 3) & 3][lslot]);                           \
        gload16(gB1 + ko, &Bl[((KB) + 3) & 3][2048 + lslot]);                    \
    }                                                                            \
    acc0 = __builtin_amdgcn_mfma_f32_16x16x32_bf16(afr[CUR], bfr[CUR][0], acc0, 0, 0, 0); \
    acc1 = __builtin_amdgcn_mfma_f32_16x16x32_bf16(afr[CUR], bfr[CUR][1], acc1, 0, 0, 0); \
    acc2 = __builtin_amdgcn_mfma_f32_16x16x32_bf16(afr[CUR], bfr[CUR][2], acc2, 0, 0, 0); \
    acc3 = __builtin_amdgcn_mfma_f32_16x16x32_bf16(afr[CUR], bfr[CUR][3], acc3, 0, 0, 0); \
    if (RDNEXT) BREAD(NXT, (KB) + 1);                                            \
    if (NEXTA)  ABUILD(CUR, (KB) + 2);                                           \
} while (0)

    for (int kbo = 0; kbo < 60; kbo += 4) {
        KSTEP(kbo + 0, 1, 2, 1, 1, 1, 0, 1);
        KSTEP(kbo + 1, 1, 2, 1, 1, 1, 1, 0);
        KSTEP(kbo + 2, 1, 2, 1, 1, 1, 0, 1);
        KSTEP(kbo + 3, 1, 2, 1, 1, 1, 1, 0);
    }
    KSTEP(60, 1, 2, 1, 1, 1, 0, 1);   // stage tile 63, build af[62]
    KSTEP(61, 1, 2, 0, 1, 1, 1, 0);   // build af[63]
    KSTEP(62, 1, 0, 0, 1, 0, 0, 1);   // read B[63]
    KSTEP(63, 0, 0, 0, 0, 0, 1, 0);   // MFMA only
#undef KSTEP
#undef BREAD
#undef ABUILD

    if (ohalf == 0) lred[(ihalf * 16 + il) * 4 + quad] = lpart;
    __syncthreads();
    if (t < 32) {
        float l = lred[t * 4] + lred[t * 4 + 1] + lred[t * 4 + 2] + lred[t * 4 + 3];
        linvl[t] = 1.f / l;
    }
    __syncthreads();

    f32x4 accs[4] = {acc0, acc1, acc2, acc3};
    #pragma unroll
    for (int t4 = 0; t4 < 4; t4++) {
        int oo = ow + t4 * 16 + il;
        float bv = bias[oo];
        #pragma unroll
        for (int rr = 0; rr < 4; rr++) {
            int irel = ihalf * 16 + quad * 4 + rr;
            float v = accs[t4][rr] * linvl[irel] + bv;
            int ii = i_tile + irel;
            out[((size_t)(b * 2048 + ii)) * 128 + oo] = v > 0.f ? v : (__expf(v) - 1.f);
        }
    }
}

extern "C" void kernel_launch(void* const* d_in, const int* in_sizes, int n_in,
                              void* d_out, int out_size, void* d_ws, size_t ws_size,
                              hipStream_t stream) {
    const float* h    = (const float*)d_in[0];
    const float* adj  = (const float*)d_in[1];
    const float* W    = (const float*)d_in[2];
    const float* av   = (const float*)d_in[3];
    const float* bias = (const float*)d_in[4];
    float* out = (float*)d_out;

    char* ws = (char*)d_ws;
    short*    whT   = (short*)ws;                       // 4 MB
    float*    f1g   = (float*)(ws + (4 << 20));         // 64 KB
    float*    f2g   = f1g + 16384;                      // 64 KB
    uint32_t* maskg = (uint32_t*)(ws + (5 << 20));      // 512 KB

    kA<<<512, 256, 0, stream>>>(h, W, av, adj, whT, f1g, f2g, maskg);
    kG2<<<512, 256, 0, stream>>>(maskg, whT, f1g, f2g, bias, out);
}